// Round 5
// baseline (1916.500 us; speedup 1.0000x reference)
//
#include <hip/hip_runtime.h>
#include <stdint.h>

constexpr int      BATCH    = 524288;
constexpr int      IN_DIM   = 128;
constexpr int      ARRAY_SZ = 262144;
constexpr uint64_t PRIME    = 2038074743ull;
constexpr uint32_t RANGE    = ARRAY_SZ - 8 + 1;  // 262137

// Block = 4 waves = 2 pairs. Pair p handles elements [tile*8 + 4p, +4);
// within a pair, wave rep r computes rep r's projection/hash/gather.
// Per-thread state: col[128] (loop-invariant) + 2 accumulators -> no spill
// (round-2 evidence: this register shape compiles to VGPR=128, scratch-free).
__global__ __launch_bounds__(256, 2)
void lma_wavepair(const float* __restrict__ x,
                  const float* __restrict__ hw,
                  const float* __restrict__ lsh,
                  const void* __restrict__ rnd_raw,
                  float* __restrict__ out_idx,   // B*128 floats (idx as f32)
                  float* __restrict__ out_val)   // B*64 floats
{
    __shared__ float s_w[2][2][4][64];   // [pair][rep][elem-in-pair][lane]

    const int tid  = threadIdx.x;
    const int lane = tid & 63;
    const int wid  = __builtin_amdgcn_readfirstlane(tid >> 6);
    const int pair = wid >> 1;
    const int rep  = wid & 1;

    // --- hash constants: detect int64 vs int32 layout of random_numbers ---
    uint64_t A, Bc, C0;
    {
        const uint64_t first8 = *reinterpret_cast<const uint64_t*>(rnd_raw);
        if (first8 == PRIME) {
            const long long* r64 = reinterpret_cast<const long long*>(rnd_raw);
            A  = (uint64_t)r64[1];
            Bc = (uint64_t)r64[2];
            C0 = (uint64_t)r64[3];
        } else {
            const int* r32 = reinterpret_cast<const int*>(rnd_raw);
            A  = (uint64_t)(uint32_t)r32[1];
            Bc = (uint64_t)(uint32_t)r32[2];
            C0 = (uint64_t)(uint32_t)r32[3];
        }
    }

    // persistent LSH column (this wave's rep): coalesced 256B loads, once.
    float col[IN_DIM];
#pragma unroll
    for (int i = 0; i < IN_DIM; ++i)
        col[i] = lsh[i * IN_DIM + rep * 64 + lane];

    const int      c      = lane >> 3;          // chunk id 0..7
    const int      s      = lane & 7;           // slot in chunk
    const uint64_t hc     = Bc * (uint64_t)c + C0;   // hoisted per-lane
    const uint32_t repoff = rep ? (uint32_t)ARRAY_SZ : 0u;

    for (int t = blockIdx.x; t < BATCH / 8; t += gridDim.x) {
        const int ebase = t * 8 + pair * 4;

        // ---- 4 elements, processed as 2 ILP-pairs ----
#pragma unroll
        for (int ep = 0; ep < 2; ++ep) {
            const int e0 = ebase + ep * 2;
            const float* xr0 = x + (size_t)e0 * IN_DIM;        // wave-uniform
            const float* xr1 = x + (size_t)(e0 + 1) * IN_DIM;  // -> s_loads
            float a0 = 0.0f, a1 = 0.0f;
            // strictly sequential i-order per output (bit-exact vs numpy;
            // absmax==0.0 in rounds 1-4). Two independent chains for ILP.
#pragma unroll
            for (int i = 0; i < IN_DIM; ++i) {
                a0 = __builtin_fmaf(xr0[i], col[i], a0);
                a1 = __builtin_fmaf(xr1[i], col[i], a1);
            }

            // phase 2 for each of the two elements
#pragma unroll
            for (int q = 0; q < 2; ++q) {
                const float acc = (q == 0) ? a0 : a1;
                const int   e   = e0 + q;
                const unsigned long long m = __ballot(acc > 0.0f);
                const uint32_t srp = (uint32_t)(m >> (c * 8)) & 0xffu;
                const uint64_t h   = (A * (uint64_t)srp + hc) % PRIME;
                const uint32_t loc = (uint32_t)h % RANGE;
                const uint32_t idx = repoff + loc + (uint32_t)s;
                const float    w   = hw[idx];
                out_idx[(size_t)e * 128 + rep * 64 + lane] = (float)idx;
                s_w[pair][rep][ep * 2 + q][lane] = w;
            }
        }
        __syncthreads();

        // ---- val stores: each wave averages 2 of its pair's 4 elements ----
#pragma unroll
        for (int q = 0; q < 2; ++q) {
            const int el = rep + q * 2;                 // 0..3 within pair
            const float w0 = s_w[pair][0][el][lane];
            const float w1 = s_w[pair][1][el][lane];
            out_val[(size_t)(ebase + el) * 64 + lane] = (w0 + w1) * 0.5f;
        }
        __syncthreads();   // protect s_w before next tile overwrites
    }
}

extern "C" void kernel_launch(void* const* d_in, const int* in_sizes, int n_in,
                              void* d_out, int out_size, void* d_ws, size_t ws_size,
                              hipStream_t stream) {
    const float* x   = (const float*)d_in[0];
    const float* hw  = (const float*)d_in[1];
    const float* lsh = (const float*)d_in[2];
    const void*  rnd = (const void*)d_in[3];

    float* out_idx = (float*)d_out;
    float* out_val = out_idx + (size_t)BATCH * 128;

    lma_wavepair<<<4096, 256, 0, stream>>>(x, hw, lsh, rnd, out_idx, out_val);
}

// Round 6
// 591.912 us; speedup vs baseline: 3.2378x; 3.2378x over previous
//
#include <hip/hip_runtime.h>
#include <stdint.h>

constexpr int      BATCH    = 524288;
constexpr int      IN_DIM   = 128;
constexpr int      ARRAY_SZ = 262144;
constexpr uint64_t PRIME    = 2038074743ull;
constexpr uint32_t RANGE    = ARRAY_SZ - 8 + 1;  // 262137
constexpr int      NTILE    = BATCH / 64;        // 64 elements per tile

// component select with compile-time index (folds in unrolled loops)
__device__ __forceinline__ float fc(const float4& v, int ii) {
    return (ii == 0) ? v.x : (ii == 1) ? v.y : (ii == 2) ? v.z : v.w;
}

__global__ __launch_bounds__(256, 2)
void lma_gemm(const float* __restrict__ x,
              const float* __restrict__ hw,
              const float* __restrict__ lsh,
              const void* __restrict__ rnd_raw,
              float* __restrict__ out_idx,   // B*128 floats (idx as f32)
              float* __restrict__ out_val)   // B*64 floats
{
    // full lsh matrix in LDS, 64 KB, column-blocks placement-permuted so the
    // 4 broadcast groups of a wave read disjoint bank quarters.
    __shared__ float s_l[128][128];

    const int tid  = threadIdx.x;
    const int lane = tid & 63;
    const int wave = __builtin_amdgcn_readfirstlane(tid >> 6);

    // --- hash constants: detect int64 vs int32 layout of random_numbers ---
    uint64_t A, Bc, C0;
    {
        const uint64_t first8 = *reinterpret_cast<const uint64_t*>(rnd_raw);
        if (first8 == PRIME) {
            const long long* r64 = reinterpret_cast<const long long*>(rnd_raw);
            A  = (uint64_t)r64[1];
            Bc = (uint64_t)r64[2];
            C0 = (uint64_t)r64[3];
        } else {
            const int* r32 = reinterpret_cast<const int*>(rnd_raw);
            A  = (uint64_t)(uint32_t)r32[1];
            Bc = (uint64_t)(uint32_t)r32[2];
            C0 = (uint64_t)(uint32_t)r32[3];
        }
    }

    // --- stage lsh once per block; store block b at slot perm(b) ---
    for (int it = 0; it < 16; ++it) {
        const int lin = it * 256 + tid;      // 4096 float4s total
        const int row = lin >> 5;
        const int hb  = lin & 31;            // half-block (4 floats)
        const int b   = hb >> 1;
        const int pb  = ((b & 3) << 2) | (b >> 2);
        const float4 v = *reinterpret_cast<const float4*>(lsh + row * 128 + hb * 4);
        *reinterpret_cast<float4*>(&s_l[row][pb * 8 + (hb & 1) * 4]) = v;
    }
    __syncthreads();

    // output block h = (lane>>4)*4 + wave: rep partners (h, h+8) are lanes
    // L and L^32 of the SAME wave -> shfl_xor(32) for the rep average.
    const int      h      = (lane >> 4) * 4 + wave;
    const int      ph     = ((h & 3) << 2) | (h >> 2);   // permuted slot
    const int      phbase = ph * 8;
    const int      rep    = h >> 3;
    const int      c      = h & 7;
    const int      eg     = (lane & 15) * 4;             // element base in tile
    const uint64_t hc     = Bc * (uint64_t)c + C0;
    const uint32_t repoff = rep ? (uint32_t)ARRAY_SZ : 0u;

    for (int t = blockIdx.x; t < NTILE; t += gridDim.x) {
        const float* xb = x + (size_t)(t * 64 + eg) * IN_DIM;

        float acc[4][8];
#pragma unroll
        for (int q = 0; q < 4; ++q)
#pragma unroll
            for (int n = 0; n < 8; ++n) acc[q][n] = 0.0f;

        // prefetch first x fragment (4 rows x float4)
        float4 nx0 = *reinterpret_cast<const float4*>(xb);
        float4 nx1 = *reinterpret_cast<const float4*>(xb + IN_DIM);
        float4 nx2 = *reinterpret_cast<const float4*>(xb + 2 * IN_DIM);
        float4 nx3 = *reinterpret_cast<const float4*>(xb + 3 * IN_DIM);

#pragma unroll 1
        for (int i4 = 0; i4 < 32; ++i4) {
            const float4 xv0 = nx0, xv1 = nx1, xv2 = nx2, xv3 = nx3;
            if (i4 < 31) {
                const float* xn = xb + (i4 + 1) * 4;
                nx0 = *reinterpret_cast<const float4*>(xn);
                nx1 = *reinterpret_cast<const float4*>(xn + IN_DIM);
                nx2 = *reinterpret_cast<const float4*>(xn + 2 * IN_DIM);
                nx3 = *reinterpret_cast<const float4*>(xn + 3 * IN_DIM);
            }
#pragma unroll
            for (int ii = 0; ii < 4; ++ii) {
                const float* lr = &s_l[i4 * 4 + ii][phbase];
                const float4 l0 = *reinterpret_cast<const float4*>(lr);
                const float4 l1 = *reinterpret_cast<const float4*>(lr + 4);
                const float xs0 = fc(xv0, ii), xs1 = fc(xv1, ii);
                const float xs2 = fc(xv2, ii), xs3 = fc(xv3, ii);
                // strictly sequential i-order per accumulator (bit-exact,
                // absmax==0.0 in rounds 1-5); 32 independent chains = ILP.
                acc[0][0] = __builtin_fmaf(xs0, l0.x, acc[0][0]);
                acc[0][1] = __builtin_fmaf(xs0, l0.y, acc[0][1]);
                acc[0][2] = __builtin_fmaf(xs0, l0.z, acc[0][2]);
                acc[0][3] = __builtin_fmaf(xs0, l0.w, acc[0][3]);
                acc[0][4] = __builtin_fmaf(xs0, l1.x, acc[0][4]);
                acc[0][5] = __builtin_fmaf(xs0, l1.y, acc[0][5]);
                acc[0][6] = __builtin_fmaf(xs0, l1.z, acc[0][6]);
                acc[0][7] = __builtin_fmaf(xs0, l1.w, acc[0][7]);
                acc[1][0] = __builtin_fmaf(xs1, l0.x, acc[1][0]);
                acc[1][1] = __builtin_fmaf(xs1, l0.y, acc[1][1]);
                acc[1][2] = __builtin_fmaf(xs1, l0.z, acc[1][2]);
                acc[1][3] = __builtin_fmaf(xs1, l0.w, acc[1][3]);
                acc[1][4] = __builtin_fmaf(xs1, l1.x, acc[1][4]);
                acc[1][5] = __builtin_fmaf(xs1, l1.y, acc[1][5]);
                acc[1][6] = __builtin_fmaf(xs1, l1.z, acc[1][6]);
                acc[1][7] = __builtin_fmaf(xs1, l1.w, acc[1][7]);
                acc[2][0] = __builtin_fmaf(xs2, l0.x, acc[2][0]);
                acc[2][1] = __builtin_fmaf(xs2, l0.y, acc[2][1]);
                acc[2][2] = __builtin_fmaf(xs2, l0.z, acc[2][2]);
                acc[2][3] = __builtin_fmaf(xs2, l0.w, acc[2][3]);
                acc[2][4] = __builtin_fmaf(xs2, l1.x, acc[2][4]);
                acc[2][5] = __builtin_fmaf(xs2, l1.y, acc[2][5]);
                acc[2][6] = __builtin_fmaf(xs2, l1.z, acc[2][6]);
                acc[2][7] = __builtin_fmaf(xs2, l1.w, acc[2][7]);
                acc[3][0] = __builtin_fmaf(xs3, l0.x, acc[3][0]);
                acc[3][1] = __builtin_fmaf(xs3, l0.y, acc[3][1]);
                acc[3][2] = __builtin_fmaf(xs3, l0.z, acc[3][2]);
                acc[3][3] = __builtin_fmaf(xs3, l0.w, acc[3][3]);
                acc[3][4] = __builtin_fmaf(xs3, l1.x, acc[3][4]);
                acc[3][5] = __builtin_fmaf(xs3, l1.y, acc[3][5]);
                acc[3][6] = __builtin_fmaf(xs3, l1.z, acc[3][6]);
                acc[3][7] = __builtin_fmaf(xs3, l1.w, acc[3][7]);
            }
        }

        // ---- phase 2: thread-local srp byte, hash, gather, exchange ----
        uint32_t loc[4];
#pragma unroll
        for (int q = 0; q < 4; ++q) {
            uint32_t srp = 0;
#pragma unroll
            for (int j = 0; j < 8; ++j)
                srp |= (acc[q][j] > 0.0f) ? (1u << j) : 0u;
            const uint64_t hh = (A * (uint64_t)srp + hc) % PRIME;
            loc[q] = (uint32_t)hh % RANGE + repoff;
        }

        float w[4][8];
#pragma unroll
        for (int q = 0; q < 4; ++q)
#pragma unroll
            for (int j = 0; j < 8; ++j)
                w[q][j] = hw[loc[q] + j];

        const int ebase = t * 64 + eg;
#pragma unroll
        for (int q = 0; q < 4; ++q) {
            const float f0 = (float)loc[q];
            float* oi = out_idx + (size_t)(ebase + q) * 128 + rep * 64 + c * 8;
            *reinterpret_cast<float4*>(oi)     = make_float4(f0, f0 + 1.f, f0 + 2.f, f0 + 3.f);
            *reinterpret_cast<float4*>(oi + 4) = make_float4(f0 + 4.f, f0 + 5.f, f0 + 6.f, f0 + 7.f);

            float v[8];
#pragma unroll
            for (int j = 0; j < 8; ++j)
                v[j] = (w[q][j] + __shfl_xor(w[q][j], 32)) * 0.5f;

            if ((q < 2) == (lane < 32)) {   // split store duty across rep halves
                float* ov = out_val + (size_t)(ebase + q) * 64 + c * 8;
                *reinterpret_cast<float4*>(ov)     = make_float4(v[0], v[1], v[2], v[3]);
                *reinterpret_cast<float4*>(ov + 4) = make_float4(v[4], v[5], v[6], v[7]);
            }
        }
    }
}

extern "C" void kernel_launch(void* const* d_in, const int* in_sizes, int n_in,
                              void* d_out, int out_size, void* d_ws, size_t ws_size,
                              hipStream_t stream) {
    const float* x   = (const float*)d_in[0];
    const float* hw  = (const float*)d_in[1];
    const float* lsh = (const float*)d_in[2];
    const void*  rnd = (const void*)d_in[3];

    float* out_idx = (float*)d_out;
    float* out_val = out_idx + (size_t)BATCH * 128;

    lma_gemm<<<1024, 256, 0, stream>>>(x, hw, lsh, rnd, out_idx, out_val);
}